// Round 16
// baseline (199.533 us; speedup 1.0000x reference)
//
#include <hip/hip_runtime.h>
#include <hip/hip_bf16.h>

#define DI __device__ __forceinline__

typedef __attribute__((ext_vector_type(8))) short short8;
typedef __attribute__((ext_vector_type(4))) short short4v;
typedef __attribute__((ext_vector_type(4))) float f32x4;

#define QSCALE 0.180336885f  // 1/sqrt(64) * log2(e)

DI short f2bf(float f) {
  __hip_bfloat16 h = __float2bfloat16(f);
  return __builtin_bit_cast(short, h);
}

DI float fexp2(float x) {
#if __has_builtin(__builtin_amdgcn_exp2f)
  return __builtin_amdgcn_exp2f(x);
#else
  return exp2f(x);
#endif
}

DI void gl16(const short* g, short* l) {
  __builtin_amdgcn_global_load_lds(
      (const __attribute__((address_space(1))) void*)g,
      (__attribute__((address_space(3))) void*)l, 16, 0, 0);
}

// ---------------------------------------------------------------------------
// All fp32->bf16 conversions in ONE launch.
// ---------------------------------------------------------------------------
__global__ __launch_bounds__(256) void convert_all(
    const float* __restrict__ q, const float* __restrict__ k,
    const float* __restrict__ v, const float* __restrict__ wq,
    const float* __restrict__ wk, const float* __restrict__ wv,
    const float* __restrict__ wo, short* __restrict__ qb,
    short* __restrict__ kb, short* __restrict__ vb, short* __restrict__ wb) {
  int z = blockIdx.z;
  const float* src;
  short* dst;
  if (z < 3) {
    src = (z == 0) ? q : (z == 1) ? k : v;
    dst = (z == 0) ? qb : (z == 1) ? kb : vb;
  } else {
    if (blockIdx.x >= 512) return;
    src = (z == 3) ? wq : (z == 4) ? wk : (z == 5) ? wv : wo;
    dst = wb + (size_t)(z - 3) * 1024 * 1024;
  }
  size_t i = ((size_t)blockIdx.x * 256 + threadIdx.x) * 8;
  float4 f0 = *(const float4*)(src + i);
  float4 f1 = *(const float4*)(src + i + 4);
  short8 o;
  o[0] = f2bf(f0.x); o[1] = f2bf(f0.y); o[2] = f2bf(f0.z); o[3] = f2bf(f0.w);
  o[4] = f2bf(f1.x); o[5] = f2bf(f1.y); o[6] = f2bf(f1.z); o[7] = f2bf(f1.w);
  *(short8*)(dst + i) = o;
}

__global__ __launch_bounds__(256) void convert_one(
    const float* __restrict__ src, short* __restrict__ dst) {
  size_t i = ((size_t)blockIdx.x * 256 + threadIdx.x) * 8;
  float4 f0 = *(const float4*)(src + i);
  float4 f1 = *(const float4*)(src + i + 4);
  short8 o;
  o[0] = f2bf(f0.x); o[1] = f2bf(f0.y); o[2] = f2bf(f0.z); o[3] = f2bf(f0.w);
  o[4] = f2bf(f1.x); o[5] = f2bf(f1.y); o[6] = f2bf(f1.z); o[7] = f2bf(f1.w);
  *(short8*)(dst + i) = o;
}

enum { OUT_F32 = 0, OUT_HEAD = 1, OUT_HEADT = 2 };

// ===========================================================================
// 256x256 8-phase GEMM v2 (proj). 512 thr = 8 waves (2M x 4N).
// Per-wave C: two 64-row m-bands (band0 = wm*64, band1 = 128+wm*64) x
// two 32-col n-bands -> 4 phases/K-tile, 16 MFMA each (4m x 2n x 2ks).
// LDS: A/B 2-buf K-tiles = 128KB. Stage order per tile (for k+1):
// P1:B-h0  P2:B-h1  P3:A-h0  P4:A-h1  (2 gl16 each).
// Waits (derived from issue order; every wave stages every half so
// per-wave vmcnt + barrier covers all waves' slices):
//   tile boundary: vmcnt(2) -> B(k+1)h0,h1 + A(k+1)h0 landed (P1,P2 safe)
//   P2 close:      vmcnt(4) -> A(k)h1 landed (P3,P4 safe); last tile: 0
// Dual barrier per phase: {stage | ds_read -> BAR -> setprio MFMA -> BAR}.
// ===========================================================================
DI void stage_half(const short* __restrict__ g, short* lds, int bmn, int k0,
                   int half, int wid_, int lrr, int lch) {
  int r0 = half * 128 + wid_ * 8;
#pragma unroll
  for (int i = 0; i < 2; ++i) {
    int rb = r0 + i * 64;
    int rr = rb + lrr;
    int sc = (lch ^ (rr & 7)) << 3;  // inverse-swizzled source chunk
    gl16(g + (size_t)(bmn + rr) * 1024 + k0 + sc, lds + rb * 64);
  }
}

DI void loadA_band(const char* bA, short8 (&afr)[4][2], int band, int wm,
                   int l15, int lq) {
#pragma unroll
  for (int mt = 0; mt < 4; ++mt)
#pragma unroll
    for (int ks = 0; ks < 2; ++ks) {
      int row = band * 128 + wm * 64 + mt * 16 + l15;
      int off = (row * 128 + ks * 64 + lq * 16) ^ ((row & 7) << 4);
      afr[mt][ks] = *(const short8*)(bA + off);
    }
}

DI void loadB_band(const char* bB, short8 (&bfr)[2][2], int nb, int wn,
                   int l15, int lq) {
#pragma unroll
  for (int nt = 0; nt < 2; ++nt)
#pragma unroll
    for (int ks = 0; ks < 2; ++ks) {
      int row = wn * 64 + nb * 32 + nt * 16 + l15;
      int off = (row * 128 + ks * 64 + lq * 16) ^ ((row & 7) << 4);
      bfr[nt][ks] = *(const short8*)(bB + off);
    }
}

template <int OMODE, int BAND, int NB>
DI void mfma16(f32x4 (&acc)[2][4][4], const short8 (&afr)[4][2],
               const short8 (&bfr)[2][2]) {
  __builtin_amdgcn_s_setprio(1);
#pragma unroll
  for (int mt = 0; mt < 4; ++mt)
#pragma unroll
    for (int nt = 0; nt < 2; ++nt)
#pragma unroll
      for (int ks = 0; ks < 2; ++ks) {
        if (OMODE == OUT_HEADT)
          acc[BAND][mt][NB * 2 + nt] = __builtin_amdgcn_mfma_f32_16x16x32_bf16(
              bfr[nt][ks], afr[mt][ks], acc[BAND][mt][NB * 2 + nt], 0, 0, 0);
        else
          acc[BAND][mt][NB * 2 + nt] = __builtin_amdgcn_mfma_f32_16x16x32_bf16(
              afr[mt][ks], bfr[nt][ks], acc[BAND][mt][NB * 2 + nt], 0, 0, 0);
      }
  __builtin_amdgcn_s_setprio(0);
}

template <int OMODE>
DI void gemm256_core(short* sA, short* sB, const short* __restrict__ A,
                     const short* __restrict__ B, void* __restrict__ Cp,
                     float scale, int bm, int bn) {
  const int tid = threadIdx.x;
  const int lane = tid & 63;
  const int wid = tid >> 6;  // 0..7
  const int wm = wid >> 2, wn = wid & 3;
  const int l15 = lane & 15, lq = lane >> 4;
  const int lrr = lane >> 3, lch = lane & 7;

  f32x4 acc[2][4][4] = {};
  short8 afr[4][2], bfr[2][2];

  // prologue: tile 0 -> buf0, order B-h0,B-h1,A-h0,A-h1 (8 loads/wave)
  stage_half(B, sB, bn, 0, 0, wid, lrr, lch);
  stage_half(B, sB, bn, 0, 1, wid, lrr, lch);
  stage_half(A, sA, bm, 0, 0, wid, lrr, lch);
  stage_half(A, sA, bm, 0, 1, wid, lrr, lch);
  asm volatile("s_waitcnt vmcnt(2)" ::: "memory");  // B+A-h0 landed
  __builtin_amdgcn_s_barrier();

  for (int k = 0; k < 16; ++k) {
    const char* bA = (const char*)(sA + (k & 1) * 16384);
    const char* bB = (const char*)(sB + (k & 1) * 16384);
    short* tA = sA + ((k + 1) & 1) * 16384;
    short* tB = sB + ((k + 1) & 1) * 16384;
    const bool stg = (k < 15);
    const int k1 = (k + 1) * 64;

    // ---- P1: band0 x nb0 ----
    if (stg) stage_half(B, tB, bn, k1, 0, wid, lrr, lch);
    loadA_band(bA, afr, 0, wm, l15, lq);
    loadB_band(bB, bfr, 0, wn, l15, lq);
    __builtin_amdgcn_s_barrier();
    mfma16<OMODE, 0, 0>(acc, afr, bfr);
    __builtin_amdgcn_s_barrier();

    // ---- P2: band0 x nb1 ----
    if (stg) stage_half(B, tB, bn, k1, 1, wid, lrr, lch);
    loadB_band(bB, bfr, 1, wn, l15, lq);
    __builtin_amdgcn_s_barrier();
    mfma16<OMODE, 0, 1>(acc, afr, bfr);
    if (stg)
      asm volatile("s_waitcnt vmcnt(4)" ::: "memory");  // A(k)h1 landed
    else
      asm volatile("s_waitcnt vmcnt(0)" ::: "memory");
    __builtin_amdgcn_s_barrier();

    // ---- P3: band1 x nb1 ----
    if (stg) stage_half(A, tA, bm, k1, 0, wid, lrr, lch);
    loadA_band(bA, afr, 1, wm, l15, lq);
    __builtin_amdgcn_s_barrier();
    mfma16<OMODE, 1, 1>(acc, afr, bfr);
    __builtin_amdgcn_s_barrier();

    // ---- P4: band1 x nb0 ----
    if (stg) stage_half(A, tA, bm, k1, 1, wid, lrr, lch);
    loadB_band(bB, bfr, 0, wn, l15, lq);
    __builtin_amdgcn_s_barrier();
    mfma16<OMODE, 1, 0>(acc, afr, bfr);
    if (k < 15) {
      asm volatile("s_waitcnt vmcnt(2)" ::: "memory");  // next B+A-h0 landed
      __builtin_amdgcn_s_barrier();
    }
  }

  // epilogue
#pragma unroll
  for (int band = 0; band < 2; ++band)
#pragma unroll
    for (int mt = 0; mt < 4; ++mt)
#pragma unroll
      for (int j = 0; j < 4; ++j)
#pragma unroll
        for (int r = 0; r < 4; ++r) {
          float val = acc[band][mt][j][r] * scale;
          if (OMODE == OUT_HEADT) {
            int f = bn + wn * 64 + j * 16 + lq * 4 + r;
            int t = bm + band * 128 + wm * 64 + mt * 16 + l15;
            int bb = t >> 11, s = t & 2047;
            int h = f >> 6, dh = f & 63;
            ((short*)Cp)[((size_t)((bb * 16 + h) * 64 + dh)) * 2048 + s] =
                f2bf(val);
          } else {
            int rowg = bm + band * 128 + wm * 64 + mt * 16 + lq * 4 + r;
            int colg = bn + wn * 64 + j * 16 + l15;
            int bb = rowg >> 11, s = rowg & 2047;
            int h = colg >> 6, dh = colg & 63;
            ((short*)Cp)[((size_t)(bb * 16 + h) * 2048 + s) * 64 + dh] =
                f2bf(val);
          }
        }
}

// 384 blocks: xcd-packed so one A-panel's 4 n-tiles share an XCD.
__global__ __launch_bounds__(512, 1) void proj_gemm256(
    const short* __restrict__ qb, const short* __restrict__ kb,
    const short* __restrict__ vb, const short* __restrict__ wq,
    const short* __restrict__ wk, const short* __restrict__ wv,
    short* __restrict__ xq, short* __restrict__ xk, short* __restrict__ xvT) {
  __shared__ __align__(16) short sA[2 * 256 * 64];
  __shared__ __align__(16) short sB[2 * 256 * 64];
  int gid = blockIdx.x;
  int xcd = gid & 7, slot = gid >> 3;
  int pg = xcd + 8 * (slot >> 2);  // global panel 0..95
  int ntile = slot & 3;
  int z = pg >> 5, pm = pg & 31;
  int bm = pm * 256, bn = ntile * 256;
  if (z == 0)
    gemm256_core<OUT_HEAD>(sA, sB, qb, wq, xq, QSCALE, bm, bn);
  else if (z == 1)
    gemm256_core<OUT_HEAD>(sA, sB, kb, wk, xk, 1.0f, bm, bn);
  else
    gemm256_core<OUT_HEADT>(sA, sB, vb, wv, xvT, 1.0f, bm, bn);
}

// ===========================================================================
// 128x128 GEMM (R14 counted-vmcnt dbuf) -- final_gemm + fallback.
// ===========================================================================
DI void stage_tile(const short* __restrict__ A, const short* __restrict__ B,
                   short* dA, short* dB, int bm, int bn, int k0, int wid,
                   int lrr, int lch) {
#pragma unroll
  for (int i = 0; i < 4; ++i) {
    int r0 = wid * 32 + i * 8;
    int rr = r0 + lrr;
    int sc = (lch ^ (rr & 7)) << 3;
    gl16(A + (size_t)(bm + rr) * 1024 + k0 + sc, dA + r0 * 64);
    gl16(B + (size_t)(bn + rr) * 1024 + k0 + sc, dB + r0 * 64);
  }
}

template <int OMODE>
DI void gemm_core(short* sA, short* sB, const short* __restrict__ A,
                  const short* __restrict__ B, void* __restrict__ Cp,
                  float scale, int bm, int bn) {
  const int tid = threadIdx.x;
  const int lane = tid & 63;
  const int wid = tid >> 6;
  const int wm = wid >> 1, wn = wid & 1;
  const int l15 = lane & 15, lq = lane >> 4;
  const int lrr = lane >> 3;
  const int lch = lane & 7;

  f32x4 acc[4][4] = {};

  stage_tile(A, B, sA, sB, bm, bn, 0, wid, lrr, lch);

  int cur = 0;
  for (int t = 0; t < 16; ++t) {
    if (t < 15) {
      stage_tile(A, B, sA + (cur ^ 1) * 8192, sB + (cur ^ 1) * 8192, bm, bn,
                 (t + 1) * 64, wid, lrr, lch);
      asm volatile("s_waitcnt vmcnt(8)" ::: "memory");
    } else {
      asm volatile("s_waitcnt vmcnt(0)" ::: "memory");
    }
    __builtin_amdgcn_s_barrier();

    const char* bA = (const char*)(sA + cur * 8192);
    const char* bB = (const char*)(sB + cur * 8192);
#pragma unroll
    for (int ks = 0; ks < 2; ++ks) {
      short8 a[4], b[4];
#pragma unroll
      for (int mt = 0; mt < 4; ++mt) {
        int row = wm * 64 + mt * 16 + l15;
        int off = (row * 128 + ks * 64 + lq * 16) ^ ((row & 7) << 4);
        a[mt] = *(const short8*)(bA + off);
      }
#pragma unroll
      for (int nt = 0; nt < 4; ++nt) {
        int row = wn * 64 + nt * 16 + l15;
        int off = (row * 128 + ks * 64 + lq * 16) ^ ((row & 7) << 4);
        b[nt] = *(const short8*)(bB + off);
      }
#pragma unroll
      for (int mt = 0; mt < 4; ++mt)
#pragma unroll
        for (int nt = 0; nt < 4; ++nt) {
          if (OMODE == OUT_HEADT)
            acc[mt][nt] = __builtin_amdgcn_mfma_f32_16x16x32_bf16(
                b[nt], a[mt], acc[mt][nt], 0, 0, 0);
          else
            acc[mt][nt] = __builtin_amdgcn_mfma_f32_16x16x32_bf16(
                a[mt], b[nt], acc[mt][nt], 0, 0, 0);
        }
    }
    __builtin_amdgcn_s_barrier();
    cur ^= 1;
  }

#pragma unroll
  for (int mt = 0; mt < 4; ++mt) {
#pragma unroll
    for (int nt = 0; nt < 4; ++nt) {
#pragma unroll
      for (int r = 0; r < 4; ++r) {
        float val = acc[mt][nt][r] * scale;
        if (OMODE == OUT_HEADT) {
          int f = bn + wn * 64 + nt * 16 + lq * 4 + r;
          int t = bm + wm * 64 + mt * 16 + l15;
          int bb = t >> 11, s = t & 2047;
          int h = f >> 6, dh = f & 63;
          ((short*)Cp)[((size_t)((bb * 16 + h) * 64 + dh)) * 2048 + s] = f2bf(val);
        } else {
          int rowg = bm + wm * 64 + mt * 16 + lq * 4 + r;
          int colg = bn + wn * 64 + nt * 16 + l15;
          if (OMODE == OUT_HEAD) {
            int bb = rowg >> 11, s = rowg & 2047;
            int h = colg >> 6, dh = colg & 63;
            ((short*)Cp)[((size_t)(bb * 16 + h) * 2048 + s) * 64 + dh] = f2bf(val);
          } else {
            ((float*)Cp)[(size_t)rowg * 1024 + colg] = val;
          }
        }
      }
    }
  }
}

DI void xcd_map(int id, int& bm, int& bn) {
  int xcd = id & 7, slot = id >> 3;
  int panel = xcd + 8 * (slot >> 3);
  int ntile = slot & 7;
  bm = panel * 128;
  bn = ntile * 128;
}

#define GEMM_LDS()                                  \
  __shared__ __align__(16) short sA[2 * 128 * 64];  \
  __shared__ __align__(16) short sB[2 * 128 * 64];

__global__ __launch_bounds__(256) void proj_oneN(
    const short* __restrict__ A, const short* __restrict__ B,
    short* __restrict__ C, float scale) {
  GEMM_LDS();
  int bm, bn;
  xcd_map(blockIdx.x, bm, bn);
  gemm_core<OUT_HEAD>(sA, sB, A, B, C, scale, bm, bn);
}

__global__ __launch_bounds__(256) void proj_oneT(
    const short* __restrict__ A, const short* __restrict__ B,
    short* __restrict__ C, float scale) {
  GEMM_LDS();
  int bm, bn;
  xcd_map(blockIdx.x, bm, bn);
  gemm_core<OUT_HEADT>(sA, sB, A, B, C, scale, bm, bn);
}

__global__ __launch_bounds__(256) void final_gemm(
    const short* __restrict__ oa, const short* __restrict__ wo,
    float* __restrict__ out) {
  GEMM_LDS();
  int bm, bn;
  xcd_map(blockIdx.x, bm, bn);
  gemm_core<OUT_F32>(sA, sB, oa, wo, out, 1.0f, bm, bn);
}

// ---------------------------------------------------------------------------
// Causal flash attention (known-good R8/R9 version, unchanged).
// ---------------------------------------------------------------------------
__global__ __launch_bounds__(512, 4) void attn_k(
    const short* __restrict__ Xq, const short* __restrict__ Xk,
    const short* __restrict__ XvT, short* __restrict__ Oa) {
  __shared__ __align__(16) short sK[2][64 * 64];
  __shared__ __align__(16) short sVT[2][64 * 64];
  __shared__ __align__(16) short sP[8][16 * 64];

  const int tid = threadIdx.x;
  const int lane = tid & 63;
  const int wid = tid >> 6;
  const int l15 = lane & 15, lq = lane >> 4;
  const int bid = blockIdx.x;
  const int ipair = bid >> 6;
  const int bh = bid & 63;
  const int b = bh >> 4, h = bh & 15;

  const short* Q = Xq + (size_t)bh * 2048 * 64;
  const short* K = Xk + (size_t)bh * 2048 * 64;
  const short* VT = XvT + (size_t)bh * 64 * 2048;

  const int srow = tid >> 3;
  const int scol = (tid & 7) * 8;
  const int soff = (srow * 128 + scol * 2) ^ ((srow & 7) << 4);

  short8 kreg, vreg;
  kreg = *(const short8*)(K + (size_t)srow * 64 + scol);
  vreg = *(const short8*)(VT + (size_t)srow * 2048 + scol);

  *(short8*)((char*)sK[0] + soff) = kreg;
  *(short8*)((char*)sVT[0] + soff) = vreg;

  short* sPw = sP[wid];
  int p = 0;

  for (int seg = 0; seg < 2; ++seg) {
    const int qt = seg ? ipair : (15 - ipair);
    const int qfirst = qt * 128 + wid * 16;
    const int qg = qfirst + l15;
    const int qlast = qfirst + 15;
    const int ntile = 2 * qt + 2;

    short8 qf[2];
#pragma unroll
    for (int ks = 0; ks < 2; ++ks)
      qf[ks] = *(const short8*)(Q + (size_t)qg * 64 + ks * 32 + lq * 8);

    float m_run = -1e30f, l_run = 0.f;
    f32x4 acc[4] = {};

    for (int kt = 0; kt < ntile; ++kt) {
      const int kv0 = kt * 64;
      __syncthreads();

      int nkt = kt + 1, nseg = seg;
      if (nkt >= ntile) { nseg = seg + 1; nkt = 0; }
      const bool hn = (nseg < 2);
      if (hn) {
        const int kn = nkt * 64;
        kreg = *(const short8*)(K + (size_t)(kn + srow) * 64 + scol);
        vreg = *(const short8*)(VT + (size_t)srow * 2048 + kn + scol);
      }

      const bool fullmask = (kv0 > qlast);
      if (!fullmask) {
        const bool needmask = (kv0 + 63 > qfirst);
        const char* bufK = (const char*)sK[p];
        const char* bufV = (const char*)sVT[p];

        f32x4 sc[4] = {};
        __builtin_amdgcn_s_setprio(1);
#pragma unroll
        for (int ks = 0; ks < 2; ++ks) {
          short8 kf[4];
#pragma unroll
          for (int nt = 0; nt < 4; ++nt) {
            int row = nt * 16 + l15;
            int off = (row * 128 + ks * 64 + lq * 16) ^ ((row & 7) << 4);
            kf[nt] = *(const short8*)(bufK + off);
          }
#pragma unroll
          for (int nt = 0; nt < 4; ++nt)
            sc[nt] = __builtin_amdgcn_mfma_f32_16x16x32_bf16(kf[nt], qf[ks],
                                                             sc[nt], 0, 0, 0);
        }
        __builtin_amdgcn_s_setprio(0);

        float pv[4][4];
        float m = -1e30f;
        if (needmask) {
#pragma unroll
          for (int nt = 0; nt < 4; ++nt)
#pragma unroll
            for (int r = 0; r < 4; ++r) {
              float s = sc[nt][r];
              if (kv0 + nt * 16 + lq * 4 + r > qg) s = -1e30f;
              pv[nt][r] = s;
              m = fmaxf(m, s);
            }
        } else {
#pragma unroll
          for (int nt = 0; nt < 4; ++nt)
#pragma unroll
            for (int r = 0; r < 4; ++r) {
              float s = sc[nt][r];
              pv[nt][r] = s;
              m = fmaxf(m, s);
            }
        }
        m = fmaxf(m, __shfl_xor(m, 16));
        m = fmaxf(m, __shfl_xor(m, 32));

        if (!__all(m - m_run <= 8.0f)) {
          const float m_new = fmaxf(m_run, m);
          const float corr = fexp2(m_run - m_new);
          l_run *= corr;
#pragma unroll
          for (int mt = 0; mt < 4; ++mt)
#pragma unroll
            for (int r = 0; r < 4; ++r) acc[mt][r] *= corr;
          m_run = m_new;
        }

        float rsum = 0.f;
#pragma unroll
        for (int nt = 0; nt < 4; ++nt)
#pragma unroll
          for (int r = 0; r < 4; ++r) {
            float e = fexp2(pv[nt][r] - m_run);
            pv[nt][r] = e;
            rsum += e;
          }
        rsum += __shfl_xor(rsum, 16);
        rsum += __shfl_xor(rsum, 32);
        l_run += rsum;

#pragma unroll
        for (int nt = 0; nt < 4; ++nt) {
          short4v pw;
#pragma unroll
          for (int r = 0; r < 4; ++r) pw[r] = f2bf(pv[nt][r]);
          int off = (l15 * 128 + nt * 32 + lq * 8) ^ ((l15 & 7) << 4);
          *(short4v*)((char*)sPw + off) = pw;
        }

        __builtin_amdgcn_s_setprio(1);
#pragma unroll
        for (int ks = 0; ks < 2; ++ks) {
          int poff = (l15 * 128 + ks * 64 + lq * 16) ^ ((l15 & 7) << 4);
          short8 pf = *(const short8*)((const char*)sPw + poff);
#pragma unroll
          for (int mt = 0; mt < 4; ++mt) {
            int row = mt * 16 + l15;
            int voff = (row * 128 + ks * 64 + lq * 16) ^ ((row & 7) << 4);
            short8 vf = *(const short8*)(bufV + voff);
            acc[mt] = __builtin_amdgcn_mfma_f32_16x16x32_bf16(vf, pf, acc[mt],
                                                              0, 0, 0);
          }
        }
        __builtin_amdgcn_s_setprio(0);
      }

      if (hn) {
        *(short8*)((char*)sK[p ^ 1] + soff) = kreg;
        *(short8*)((char*)sVT[p ^ 1] + soff) = vreg;
      }
      p ^= 1;
    }

    const float rl = 1.0f / l_run;
    short* orow = Oa + ((size_t)(b * 2048 + qg)) * 1024 + h * 64;
#pragma unroll
    for (int mt = 0; mt < 4; ++mt) {
      short4v o;
#pragma unroll
      for (int r = 0; r < 4; ++r) o[r] = f2bf(acc[mt][r] * rl);
      *(short4v*)(orow + mt * 16 + lq * 4) = o;
    }
  }
}

// ---------------------------------------------------------------------------
extern "C" void kernel_launch(void* const* d_in, const int* in_sizes, int n_in,
                              void* d_out, int out_size, void* d_ws,
                              size_t ws_size, hipStream_t stream) {
  const float* q = (const float*)d_in[0];
  const float* k = (const float*)d_in[1];
  const float* v = (const float*)d_in[2];
  const float* Wq = (const float*)d_in[3];
  const float* Wk = (const float*)d_in[4];
  const float* Wv = (const float*)d_in[5];
  const float* Wo = (const float*)d_in[6];

  char* ws = (char*)d_ws;
  short* wq_b = (short*)(ws + (0ull << 20));
  short* wk_b = (short*)(ws + (2ull << 20));
  short* wv_b = (short*)(ws + (4ull << 20));
  short* wo_b = (short*)(ws + (6ull << 20));
  short* xq  = (short*)(ws + (8ull << 20));
  short* xk  = (short*)(ws + (24ull << 20));
  short* xvT = (short*)(ws + (56ull << 20));

  if (ws_size >= (122ull << 20)) {
    short* qb = (short*)(ws + (72ull << 20));
    short* kb = (short*)(ws + (88ull << 20));
    short* vb = (short*)(ws + (104ull << 20));
    short* oa = qb;  // qb dead after proj

    convert_all<<<dim3(4096, 1, 7), 256, 0, stream>>>(q, k, v, Wq, Wk, Wv, Wo,
                                                      qb, kb, vb, wq_b);
    proj_gemm256<<<dim3(384), 512, 0, stream>>>(qb, kb, vb, wq_b, wk_b, wv_b,
                                                xq, xk, xvT);
    attn_k<<<dim3(512), 512, 0, stream>>>(xq, xk, xvT, oa);
    final_gemm<<<dim3(512), 256, 0, stream>>>(oa, wo_b, (float*)d_out);
  } else {
    short* X = (short*)(ws + (8ull << 20));
    short* xq2 = (short*)(ws + (24ull << 20));
    short* xk2 = (short*)(ws + (40ull << 20));
    short* xvT2 = (short*)(ws + (56ull << 20));
    short* oa2 = (short*)(ws + (72ull << 20));

    convert_one<<<dim3(512), 256, 0, stream>>>(Wq, wq_b);
    convert_one<<<dim3(512), 256, 0, stream>>>(Wk, wk_b);
    convert_one<<<dim3(512), 256, 0, stream>>>(Wv, wv_b);
    convert_one<<<dim3(512), 256, 0, stream>>>(Wo, wo_b);
    convert_one<<<dim3(4096), 256, 0, stream>>>(q, X);
    proj_oneN<<<dim3(512), 256, 0, stream>>>(X, wq_b, xq2, QSCALE);
    convert_one<<<dim3(4096), 256, 0, stream>>>(k, X);
    proj_oneN<<<dim3(512), 256, 0, stream>>>(X, wk_b, xk2, 1.0f);
    convert_one<<<dim3(4096), 256, 0, stream>>>(v, X);
    proj_oneT<<<dim3(512), 256, 0, stream>>>(X, wv_b, xvT2, 1.0f);
    attn_k<<<dim3(512), 512, 0, stream>>>(xq2, xk2, xvT2, oa2);
    final_gemm<<<dim3(512), 256, 0, stream>>>(oa2, wo_b, (float*)d_out);
  }
}

// Round 17
// 174.514 us; speedup vs baseline: 1.1434x; 1.1434x over previous
//
#include <hip/hip_runtime.h>
#include <hip/hip_bf16.h>

#define DI __device__ __forceinline__

typedef __attribute__((ext_vector_type(8))) short short8;
typedef __attribute__((ext_vector_type(4))) short short4v;
typedef __attribute__((ext_vector_type(4))) float f32x4;

// Q pre-scale: 1/sqrt(64) * log2(e)  (exp2-domain softmax)
#define QSCALE 0.180336885f

// RNE float -> bf16 via native fptrunc (compiler packs v_cvt_pk_bf16_f32)
DI short f2bf(float f) {
  __hip_bfloat16 h = __float2bfloat16(f);
  return __builtin_bit_cast(short, h);
}

DI float fexp2(float x) {
#if __has_builtin(__builtin_amdgcn_exp2f)
  return __builtin_amdgcn_exp2f(x);
#else
  return exp2f(x);
#endif
}

// async global->LDS, 16B per lane. LDS dest = wave-uniform base + lane*16.
DI void gl16(const short* g, short* l) {
  __builtin_amdgcn_global_load_lds(
      (const __attribute__((address_space(1))) void*)g,
      (__attribute__((address_space(3))) void*)l, 16, 0, 0);
}

// ---------------------------------------------------------------------------
// All fp32->bf16 conversions in ONE launch.
// z 0..2: q/k/v [8192x1024] (4096 blocks x 8 elems). z 3..6: W* (512 blocks).
// ---------------------------------------------------------------------------
__global__ __launch_bounds__(256) void convert_all(
    const float* __restrict__ q, const float* __restrict__ k,
    const float* __restrict__ v, const float* __restrict__ wq,
    const float* __restrict__ wk, const float* __restrict__ wv,
    const float* __restrict__ wo, short* __restrict__ qb,
    short* __restrict__ kb, short* __restrict__ vb, short* __restrict__ wb) {
  int z = blockIdx.z;
  const float* src;
  short* dst;
  if (z < 3) {
    src = (z == 0) ? q : (z == 1) ? k : v;
    dst = (z == 0) ? qb : (z == 1) ? kb : vb;
  } else {
    if (blockIdx.x >= 512) return;
    src = (z == 3) ? wq : (z == 4) ? wk : (z == 5) ? wv : wo;
    dst = wb + (size_t)(z - 3) * 1024 * 1024;
  }
  size_t i = ((size_t)blockIdx.x * 256 + threadIdx.x) * 8;
  float4 f0 = *(const float4*)(src + i);
  float4 f1 = *(const float4*)(src + i + 4);
  short8 o;
  o[0] = f2bf(f0.x); o[1] = f2bf(f0.y); o[2] = f2bf(f0.z); o[3] = f2bf(f0.w);
  o[4] = f2bf(f1.x); o[5] = f2bf(f1.y); o[6] = f2bf(f1.z); o[7] = f2bf(f1.w);
  *(short8*)(dst + i) = o;
}

// single src->dst convert (fallback path)
__global__ __launch_bounds__(256) void convert_one(
    const float* __restrict__ src, short* __restrict__ dst) {
  size_t i = ((size_t)blockIdx.x * 256 + threadIdx.x) * 8;
  float4 f0 = *(const float4*)(src + i);
  float4 f1 = *(const float4*)(src + i + 4);
  short8 o;
  o[0] = f2bf(f0.x); o[1] = f2bf(f0.y); o[2] = f2bf(f0.z); o[3] = f2bf(f0.w);
  o[4] = f2bf(f1.x); o[5] = f2bf(f1.y); o[6] = f2bf(f1.z); o[7] = f2bf(f1.w);
  *(short8*)(dst + i) = o;
}

// ---------------------------------------------------------------------------
// bf16 GEMM core: double-buffered gl16 staging with COUNTED vmcnt (T4).
// Per K-step: issue 8 gl16 for tile t+1 into buf^1, s_waitcnt vmcnt(8)
// (waits only the 8 OLDER tile-t loads), raw s_barrier, compute buf,
// raw s_barrier (no drain). Prefetch loads stay in flight across barriers.
// Best-measured GEMM structure of this session (R14: proj 72us, total 173.9).
// ---------------------------------------------------------------------------
enum { OUT_F32 = 0, OUT_HEAD = 1, OUT_HEADT = 2 };

DI void stage_tile(const short* __restrict__ A, const short* __restrict__ B,
                   short* dA, short* dB, int bm, int bn, int k0, int wid,
                   int lrr, int lch) {
#pragma unroll
  for (int i = 0; i < 4; ++i) {
    int r0 = wid * 32 + i * 8;
    int rr = r0 + lrr;
    int sc = (lch ^ (rr & 7)) << 3;  // inverse-swizzled source chunk (shorts)
    gl16(A + (size_t)(bm + rr) * 1024 + k0 + sc, dA + r0 * 64);
    gl16(B + (size_t)(bn + rr) * 1024 + k0 + sc, dB + r0 * 64);
  }
}

template <int OMODE>
DI void gemm_core(short* sA, short* sB, const short* __restrict__ A,
                  const short* __restrict__ B, void* __restrict__ Cp,
                  float scale, int bm, int bn) {
  const int tid = threadIdx.x;
  const int lane = tid & 63;
  const int wid = tid >> 6;
  const int wm = wid >> 1, wn = wid & 1;
  const int l15 = lane & 15, lq = lane >> 4;
  const int lrr = lane >> 3;  // row within 8-row group
  const int lch = lane & 7;   // 16B chunk within 128B row

  f32x4 acc[4][4] = {};

  // prologue: tile 0 -> buffer 0 (8 loads in flight)
  stage_tile(A, B, sA, sB, bm, bn, 0, wid, lrr, lch);

  int cur = 0;
  for (int t = 0; t < 16; ++t) {
    if (t < 15) {
      // issue tile t+1 (8 more loads) then wait ONLY for tile t's 8
      stage_tile(A, B, sA + (cur ^ 1) * 8192, sB + (cur ^ 1) * 8192, bm, bn,
                 (t + 1) * 64, wid, lrr, lch);
      asm volatile("s_waitcnt vmcnt(8)" ::: "memory");
    } else {
      asm volatile("s_waitcnt vmcnt(0)" ::: "memory");
    }
    __builtin_amdgcn_s_barrier();  // all waves' tile-t loads landed

    const char* bA = (const char*)(sA + cur * 8192);
    const char* bB = (const char*)(sB + cur * 8192);
#pragma unroll
    for (int ks = 0; ks < 2; ++ks) {
      short8 a[4], b[4];
#pragma unroll
      for (int mt = 0; mt < 4; ++mt) {
        int row = wm * 64 + mt * 16 + l15;
        int off = (row * 128 + ks * 64 + lq * 16) ^ ((row & 7) << 4);
        a[mt] = *(const short8*)(bA + off);
      }
#pragma unroll
      for (int nt = 0; nt < 4; ++nt) {
        int row = wn * 64 + nt * 16 + l15;
        int off = (row * 128 + ks * 64 + lq * 16) ^ ((row & 7) << 4);
        b[nt] = *(const short8*)(bB + off);
      }
#pragma unroll
      for (int mt = 0; mt < 4; ++mt)
#pragma unroll
        for (int nt = 0; nt < 4; ++nt) {
          if (OMODE == OUT_HEADT)
            acc[mt][nt] = __builtin_amdgcn_mfma_f32_16x16x32_bf16(
                b[nt], a[mt], acc[mt][nt], 0, 0, 0);
          else
            acc[mt][nt] = __builtin_amdgcn_mfma_f32_16x16x32_bf16(
                a[mt], b[nt], acc[mt][nt], 0, 0, 0);
        }
    }
    __builtin_amdgcn_s_barrier();  // all waves done reading buf[cur]
    cur ^= 1;
  }

  // ---- epilogue (R9 layout) ----
#pragma unroll
  for (int mt = 0; mt < 4; ++mt) {
#pragma unroll
    for (int nt = 0; nt < 4; ++nt) {
#pragma unroll
      for (int r = 0; r < 4; ++r) {
        float val = acc[mt][nt][r] * scale;
        if (OMODE == OUT_HEADT) {
          int f = bn + wn * 64 + nt * 16 + lq * 4 + r;
          int t = bm + wm * 64 + mt * 16 + l15;
          int bb = t >> 11, s = t & 2047;
          int h = f >> 6, dh = f & 63;
          ((short*)Cp)[((size_t)((bb * 16 + h) * 64 + dh)) * 2048 + s] = f2bf(val);
        } else {
          int rowg = bm + wm * 64 + mt * 16 + lq * 4 + r;
          int colg = bn + wn * 64 + nt * 16 + l15;
          if (OMODE == OUT_HEAD) {
            int bb = rowg >> 11, s = rowg & 2047;
            int h = colg >> 6, dh = colg & 63;
            ((short*)Cp)[((size_t)(bb * 16 + h) * 2048 + s) * 64 + dh] = f2bf(val);
          } else {
            ((float*)Cp)[(size_t)rowg * 1024 + colg] = val;
          }
        }
      }
    }
  }
}

// XCD-aware tile mapping: 8 n-tiles of one A row-panel run consecutively on
// ONE XCD (id&7 = xcd under round-robin dispatch) -> A panel read once.
DI void xcd_map(int id, int& bm, int& bn) {
  int xcd = id & 7, slot = id >> 3;
  int panel = xcd + 8 * (slot >> 3);
  int ntile = slot & 7;
  bm = panel * 128;
  bn = ntile * 128;
}

#define GEMM_LDS()                                  \
  __shared__ __align__(16) short sA[2 * 128 * 64];  \
  __shared__ __align__(16) short sB[2 * 128 * 64];

__global__ __launch_bounds__(256) void proj_gemm3(
    const short* __restrict__ qb, const short* __restrict__ kb,
    const short* __restrict__ vb, const short* __restrict__ wq,
    const short* __restrict__ wk, const short* __restrict__ wv,
    short* __restrict__ xq, short* __restrict__ xk, short* __restrict__ xvT) {
  GEMM_LDS();
  int z = blockIdx.z;
  int bm, bn;
  xcd_map(blockIdx.x, bm, bn);
  if (z == 0) {
    gemm_core<OUT_HEAD>(sA, sB, qb, wq, xq, QSCALE, bm, bn);
  } else if (z == 1) {
    gemm_core<OUT_HEAD>(sA, sB, kb, wk, xk, 1.0f, bm, bn);
  } else {
    gemm_core<OUT_HEADT>(sA, sB, vb, wv, xvT, 1.0f, bm, bn);
  }
}

__global__ __launch_bounds__(256) void proj_oneN(
    const short* __restrict__ A, const short* __restrict__ B,
    short* __restrict__ C, float scale) {
  GEMM_LDS();
  int bm, bn;
  xcd_map(blockIdx.x, bm, bn);
  gemm_core<OUT_HEAD>(sA, sB, A, B, C, scale, bm, bn);
}

__global__ __launch_bounds__(256) void proj_oneT(
    const short* __restrict__ A, const short* __restrict__ B,
    short* __restrict__ C, float scale) {
  GEMM_LDS();
  int bm, bn;
  xcd_map(blockIdx.x, bm, bn);
  gemm_core<OUT_HEADT>(sA, sB, A, B, C, scale, bm, bn);
}

__global__ __launch_bounds__(256) void final_gemm(
    const short* __restrict__ oa, const short* __restrict__ wo,
    float* __restrict__ out) {
  GEMM_LDS();
  int bm, bn;
  xcd_map(blockIdx.x, bm, bn);
  gemm_core<OUT_F32>(sA, sB, oa, wo, out, 1.0f, bm, bn);
}

// ---------------------------------------------------------------------------
// Causal flash attention (known-good R8/R9 version).
// 512 threads = 8 waves; 128-row q-supertile; pairs (i, 15-i) -> 34 KV
// tiles/block, 512 blocks. Double-buffered K/V^T LDS, ONE barrier per tile.
// LDS = 32KB (K,VT dbuf) + 16KB (P) = 48KB.
// ---------------------------------------------------------------------------
__global__ __launch_bounds__(512, 4) void attn_k(
    const short* __restrict__ Xq, const short* __restrict__ Xk,
    const short* __restrict__ XvT, short* __restrict__ Oa) {
  __shared__ __align__(16) short sK[2][64 * 64];
  __shared__ __align__(16) short sVT[2][64 * 64];
  __shared__ __align__(16) short sP[8][16 * 64];

  const int tid = threadIdx.x;
  const int lane = tid & 63;
  const int wid = tid >> 6;  // 0..7
  const int l15 = lane & 15, lq = lane >> 4;
  const int bid = blockIdx.x;
  const int ipair = bid >> 6;  // 0..7
  const int bh = bid & 63;     // same-bh blocks land on same XCD
  const int b = bh >> 4, h = bh & 15;

  const short* Q = Xq + (size_t)bh * 2048 * 64;
  const short* K = Xk + (size_t)bh * 2048 * 64;
  const short* VT = XvT + (size_t)bh * 64 * 2048;

  const int srow = tid >> 3;       // 0..63
  const int scol = (tid & 7) * 8;  // 0..56
  const int soff = (srow * 128 + scol * 2) ^ ((srow & 7) << 4);

  short8 kreg, vreg;
  kreg = *(const short8*)(K + (size_t)srow * 64 + scol);
  vreg = *(const short8*)(VT + (size_t)srow * 2048 + scol);

  *(short8*)((char*)sK[0] + soff) = kreg;
  *(short8*)((char*)sVT[0] + soff) = vreg;

  short* sPw = sP[wid];
  int p = 0;

  for (int seg = 0; seg < 2; ++seg) {
    const int qt = seg ? ipair : (15 - ipair);  // long supertile first
    const int qfirst = qt * 128 + wid * 16;
    const int qg = qfirst + l15;
    const int qlast = qfirst + 15;
    const int ntile = 2 * qt + 2;

    short8 qf[2];
#pragma unroll
    for (int ks = 0; ks < 2; ++ks)
      qf[ks] = *(const short8*)(Q + (size_t)qg * 64 + ks * 32 + lq * 8);

    float m_run = -1e30f, l_run = 0.f;
    f32x4 acc[4] = {};

    for (int kt = 0; kt < ntile; ++kt) {
      const int kv0 = kt * 64;
      __syncthreads();

      int nkt = kt + 1, nseg = seg;
      if (nkt >= ntile) { nseg = seg + 1; nkt = 0; }
      const bool hn = (nseg < 2);
      if (hn) {
        const int kn = nkt * 64;
        kreg = *(const short8*)(K + (size_t)(kn + srow) * 64 + scol);
        vreg = *(const short8*)(VT + (size_t)srow * 2048 + kn + scol);
      }

      const bool fullmask = (kv0 > qlast);
      if (!fullmask) {
        const bool needmask = (kv0 + 63 > qfirst);
        const char* bufK = (const char*)sK[p];
        const char* bufV = (const char*)sVT[p];

        f32x4 sc[4] = {};
        __builtin_amdgcn_s_setprio(1);
#pragma unroll
        for (int ks = 0; ks < 2; ++ks) {
          short8 kf[4];
#pragma unroll
          for (int nt = 0; nt < 4; ++nt) {
            int row = nt * 16 + l15;
            int off = (row * 128 + ks * 64 + lq * 16) ^ ((row & 7) << 4);
            kf[nt] = *(const short8*)(bufK + off);
          }
#pragma unroll
          for (int nt = 0; nt < 4; ++nt)
            sc[nt] = __builtin_amdgcn_mfma_f32_16x16x32_bf16(kf[nt], qf[ks],
                                                             sc[nt], 0, 0, 0);
        }
        __builtin_amdgcn_s_setprio(0);

        float pv[4][4];
        float m = -1e30f;
        if (needmask) {
#pragma unroll
          for (int nt = 0; nt < 4; ++nt)
#pragma unroll
            for (int r = 0; r < 4; ++r) {
              float s = sc[nt][r];
              if (kv0 + nt * 16 + lq * 4 + r > qg) s = -1e30f;
              pv[nt][r] = s;
              m = fmaxf(m, s);
            }
        } else {
#pragma unroll
          for (int nt = 0; nt < 4; ++nt)
#pragma unroll
            for (int r = 0; r < 4; ++r) {
              float s = sc[nt][r];
              pv[nt][r] = s;
              m = fmaxf(m, s);
            }
        }
        m = fmaxf(m, __shfl_xor(m, 16));
        m = fmaxf(m, __shfl_xor(m, 32));

        if (!__all(m - m_run <= 8.0f)) {
          const float m_new = fmaxf(m_run, m);
          const float corr = fexp2(m_run - m_new);
          l_run *= corr;
#pragma unroll
          for (int mt = 0; mt < 4; ++mt)
#pragma unroll
            for (int r = 0; r < 4; ++r) acc[mt][r] *= corr;
          m_run = m_new;
        }

        float rsum = 0.f;
#pragma unroll
        for (int nt = 0; nt < 4; ++nt)
#pragma unroll
          for (int r = 0; r < 4; ++r) {
            float e = fexp2(pv[nt][r] - m_run);
            pv[nt][r] = e;
            rsum += e;
          }
        rsum += __shfl_xor(rsum, 16);
        rsum += __shfl_xor(rsum, 32);
        l_run += rsum;

#pragma unroll
        for (int nt = 0; nt < 4; ++nt) {
          short4v pw;
#pragma unroll
          for (int r = 0; r < 4; ++r) pw[r] = f2bf(pv[nt][r]);
          int off = (l15 * 128 + nt * 32 + lq * 8) ^ ((l15 & 7) << 4);
          *(short4v*)((char*)sPw + off) = pw;
        }

        __builtin_amdgcn_s_setprio(1);
#pragma unroll
        for (int ks = 0; ks < 2; ++ks) {
          int poff = (l15 * 128 + ks * 64 + lq * 16) ^ ((l15 & 7) << 4);
          short8 pf = *(const short8*)((const char*)sPw + poff);
#pragma unroll
          for (int mt = 0; mt < 4; ++mt) {
            int row = mt * 16 + l15;
            int voff = (row * 128 + ks * 64 + lq * 16) ^ ((row & 7) << 4);
            short8 vf = *(const short8*)(bufV + voff);
            acc[mt] = __builtin_amdgcn_mfma_f32_16x16x32_bf16(vf, pf, acc[mt],
                                                              0, 0, 0);
          }
        }
        __builtin_amdgcn_s_setprio(0);
      }

      if (hn) {
        *(short8*)((char*)sK[p ^ 1] + soff) = kreg;
        *(short8*)((char*)sVT[p ^ 1] + soff) = vreg;
      }
      p ^= 1;
    }

    const float rl = 1.0f / l_run;
    short* orow = Oa + ((size_t)(b * 2048 + qg)) * 1024 + h * 64;
#pragma unroll
    for (int mt = 0; mt < 4; ++mt) {
      short4v o;
#pragma unroll
      for (int r = 0; r < 4; ++r) o[r] = f2bf(acc[mt][r] * rl);
      *(short4v*)(orow + mt * 16 + lq * 4) = o;
    }
  }
}

// ---------------------------------------------------------------------------
extern "C" void kernel_launch(void* const* d_in, const int* in_sizes, int n_in,
                              void* d_out, int out_size, void* d_ws,
                              size_t ws_size, hipStream_t stream) {
  const float* q = (const float*)d_in[0];
  const float* k = (const float*)d_in[1];
  const float* v = (const float*)d_in[2];
  const float* Wq = (const float*)d_in[3];
  const float* Wk = (const float*)d_in[4];
  const float* Wv = (const float*)d_in[5];
  const float* Wo = (const float*)d_in[6];

  char* ws = (char*)d_ws;
  short* wq_b = (short*)(ws + (0ull << 20));
  short* wk_b = (short*)(ws + (2ull << 20));
  short* wv_b = (short*)(ws + (4ull << 20));
  short* wo_b = (short*)(ws + (6ull << 20));
  short* xq  = (short*)(ws + (8ull << 20));    // 16 MB each, [B,H,S,Dh] bf16
  short* xk  = (short*)(ws + (24ull << 20));
  short* xvT = (short*)(ws + (56ull << 20));   // [B,H,Dh,S] bf16

  if (ws_size >= (122ull << 20)) {
    short* qb = (short*)(ws + (72ull << 20));  // 16 MB each, [B*S, D] bf16
    short* kb = (short*)(ws + (88ull << 20));
    short* vb = (short*)(ws + (104ull << 20));
    short* oa = qb;  // qb dead after proj_gemm3

    convert_all<<<dim3(4096, 1, 7), 256, 0, stream>>>(q, k, v, Wq, Wk, Wv, Wo,
                                                      qb, kb, vb, wq_b);
    proj_gemm3<<<dim3(512, 1, 3), 256, 0, stream>>>(qb, kb, vb, wq_b, wk_b,
                                                    wv_b, xq, xk, xvT);
    attn_k<<<dim3(512), 512, 0, stream>>>(xq, xk, xvT, oa);
    final_gemm<<<dim3(512), 256, 0, stream>>>(oa, wo_b, (float*)d_out);
  } else {
    // ping-pong fallback: one 16 MB staging buffer, sequential per-z
    short* X = (short*)(ws + (8ull << 20));
    short* xq2 = (short*)(ws + (24ull << 20));
    short* xk2 = (short*)(ws + (40ull << 20));
    short* xvT2 = (short*)(ws + (56ull << 20));
    short* oa2 = (short*)(ws + (72ull << 20));

    convert_one<<<dim3(512), 256, 0, stream>>>(Wq, wq_b);
    convert_one<<<dim3(512), 256, 0, stream>>>(Wk, wk_b);
    convert_one<<<dim3(512), 256, 0, stream>>>(Wv, wv_b);
    convert_one<<<dim3(512), 256, 0, stream>>>(Wo, wo_b);
    convert_one<<<dim3(4096), 256, 0, stream>>>(q, X);
    proj_oneN<<<dim3(512), 256, 0, stream>>>(X, wq_b, xq2, QSCALE);
    convert_one<<<dim3(4096), 256, 0, stream>>>(k, X);
    proj_oneN<<<dim3(512), 256, 0, stream>>>(X, wk_b, xk2, 1.0f);
    convert_one<<<dim3(4096), 256, 0, stream>>>(v, X);
    proj_oneT<<<dim3(512), 256, 0, stream>>>(X, wv_b, xvT2, 1.0f);
    attn_k<<<dim3(512), 512, 0, stream>>>(xq2, xk2, xvT2, oa2);
    final_gemm<<<dim3(512), 256, 0, stream>>>(oa2, wo_b, (float*)d_out);
  }
}

// Round 18
// 173.402 us; speedup vs baseline: 1.1507x; 1.0064x over previous
//
#include <hip/hip_runtime.h>
#include <hip/hip_bf16.h>

#define DI __device__ __forceinline__

typedef __attribute__((ext_vector_type(8))) short short8;
typedef __attribute__((ext_vector_type(4))) short short4v;
typedef __attribute__((ext_vector_type(4))) float f32x4;

// Q pre-scale: 1/sqrt(64) * log2(e)  (exp2-domain softmax)
#define QSCALE 0.180336885f

// RNE float -> bf16 via native fptrunc (compiler packs v_cvt_pk_bf16_f32)
DI short f2bf(float f) {
  __hip_bfloat16 h = __float2bfloat16(f);
  return __builtin_bit_cast(short, h);
}

DI float fexp2(float x) {
#if __has_builtin(__builtin_amdgcn_exp2f)
  return __builtin_amdgcn_exp2f(x);
#else
  return exp2f(x);
#endif
}

// async global->LDS, 16B per lane. LDS dest = wave-uniform base + lane*16.
DI void gl16(const short* g, short* l) {
  __builtin_amdgcn_global_load_lds(
      (const __attribute__((address_space(1))) void*)g,
      (__attribute__((address_space(3))) void*)l, 16, 0, 0);
}

// ---------------------------------------------------------------------------
// All fp32->bf16 conversions in ONE launch.
// z 0..2: q/k/v [8192x1024] (4096 blocks x 8 elems). z 3..6: W* (512 blocks).
// ---------------------------------------------------------------------------
__global__ __launch_bounds__(256) void convert_all(
    const float* __restrict__ q, const float* __restrict__ k,
    const float* __restrict__ v, const float* __restrict__ wq,
    const float* __restrict__ wk, const float* __restrict__ wv,
    const float* __restrict__ wo, short* __restrict__ qb,
    short* __restrict__ kb, short* __restrict__ vb, short* __restrict__ wb) {
  int z = blockIdx.z;
  const float* src;
  short* dst;
  if (z < 3) {
    src = (z == 0) ? q : (z == 1) ? k : v;
    dst = (z == 0) ? qb : (z == 1) ? kb : vb;
  } else {
    if (blockIdx.x >= 512) return;
    src = (z == 3) ? wq : (z == 4) ? wk : (z == 5) ? wv : wo;
    dst = wb + (size_t)(z - 3) * 1024 * 1024;
  }
  size_t i = ((size_t)blockIdx.x * 256 + threadIdx.x) * 8;
  float4 f0 = *(const float4*)(src + i);
  float4 f1 = *(const float4*)(src + i + 4);
  short8 o;
  o[0] = f2bf(f0.x); o[1] = f2bf(f0.y); o[2] = f2bf(f0.z); o[3] = f2bf(f0.w);
  o[4] = f2bf(f1.x); o[5] = f2bf(f1.y); o[6] = f2bf(f1.z); o[7] = f2bf(f1.w);
  *(short8*)(dst + i) = o;
}

// single src->dst convert (fallback path)
__global__ __launch_bounds__(256) void convert_one(
    const float* __restrict__ src, short* __restrict__ dst) {
  size_t i = ((size_t)blockIdx.x * 256 + threadIdx.x) * 8;
  float4 f0 = *(const float4*)(src + i);
  float4 f1 = *(const float4*)(src + i + 4);
  short8 o;
  o[0] = f2bf(f0.x); o[1] = f2bf(f0.y); o[2] = f2bf(f0.z); o[3] = f2bf(f0.w);
  o[4] = f2bf(f1.x); o[5] = f2bf(f1.y); o[6] = f2bf(f1.z); o[7] = f2bf(f1.w);
  *(short8*)(dst + i) = o;
}

// ---------------------------------------------------------------------------
// bf16 GEMM core: double-buffered gl16 staging with COUNTED vmcnt (T4).
// Best-measured GEMM structure of this session (R14: proj 72us).
// ---------------------------------------------------------------------------
enum { OUT_F32 = 0, OUT_HEAD = 1, OUT_HEADT = 2 };

DI void stage_tile(const short* __restrict__ A, const short* __restrict__ B,
                   short* dA, short* dB, int bm, int bn, int k0, int wid,
                   int lrr, int lch) {
#pragma unroll
  for (int i = 0; i < 4; ++i) {
    int r0 = wid * 32 + i * 8;
    int rr = r0 + lrr;
    int sc = (lch ^ (rr & 7)) << 3;  // inverse-swizzled source chunk (shorts)
    gl16(A + (size_t)(bm + rr) * 1024 + k0 + sc, dA + r0 * 64);
    gl16(B + (size_t)(bn + rr) * 1024 + k0 + sc, dB + r0 * 64);
  }
}

template <int OMODE>
DI void gemm_core(short* sA, short* sB, const short* __restrict__ A,
                  const short* __restrict__ B, void* __restrict__ Cp,
                  float scale, int bm, int bn) {
  const int tid = threadIdx.x;
  const int lane = tid & 63;
  const int wid = tid >> 6;
  const int wm = wid >> 1, wn = wid & 1;
  const int l15 = lane & 15, lq = lane >> 4;
  const int lrr = lane >> 3;  // row within 8-row group
  const int lch = lane & 7;   // 16B chunk within 128B row

  f32x4 acc[4][4] = {};

  stage_tile(A, B, sA, sB, bm, bn, 0, wid, lrr, lch);

  int cur = 0;
  for (int t = 0; t < 16; ++t) {
    if (t < 15) {
      stage_tile(A, B, sA + (cur ^ 1) * 8192, sB + (cur ^ 1) * 8192, bm, bn,
                 (t + 1) * 64, wid, lrr, lch);
      asm volatile("s_waitcnt vmcnt(8)" ::: "memory");
    } else {
      asm volatile("s_waitcnt vmcnt(0)" ::: "memory");
    }
    __builtin_amdgcn_s_barrier();  // all waves' tile-t loads landed

    const char* bA = (const char*)(sA + cur * 8192);
    const char* bB = (const char*)(sB + cur * 8192);
#pragma unroll
    for (int ks = 0; ks < 2; ++ks) {
      short8 a[4], b[4];
#pragma unroll
      for (int mt = 0; mt < 4; ++mt) {
        int row = wm * 64 + mt * 16 + l15;
        int off = (row * 128 + ks * 64 + lq * 16) ^ ((row & 7) << 4);
        a[mt] = *(const short8*)(bA + off);
      }
#pragma unroll
      for (int nt = 0; nt < 4; ++nt) {
        int row = wn * 64 + nt * 16 + l15;
        int off = (row * 128 + ks * 64 + lq * 16) ^ ((row & 7) << 4);
        b[nt] = *(const short8*)(bB + off);
      }
#pragma unroll
      for (int mt = 0; mt < 4; ++mt)
#pragma unroll
        for (int nt = 0; nt < 4; ++nt) {
          if (OMODE == OUT_HEADT)
            acc[mt][nt] = __builtin_amdgcn_mfma_f32_16x16x32_bf16(
                b[nt], a[mt], acc[mt][nt], 0, 0, 0);
          else
            acc[mt][nt] = __builtin_amdgcn_mfma_f32_16x16x32_bf16(
                a[mt], b[nt], acc[mt][nt], 0, 0, 0);
        }
    }
    __builtin_amdgcn_s_barrier();  // all waves done reading buf[cur]
    cur ^= 1;
  }

  // ---- epilogue (R9 layout) ----
#pragma unroll
  for (int mt = 0; mt < 4; ++mt) {
#pragma unroll
    for (int nt = 0; nt < 4; ++nt) {
#pragma unroll
      for (int r = 0; r < 4; ++r) {
        float val = acc[mt][nt][r] * scale;
        if (OMODE == OUT_HEADT) {
          int f = bn + wn * 64 + nt * 16 + lq * 4 + r;
          int t = bm + wm * 64 + mt * 16 + l15;
          int bb = t >> 11, s = t & 2047;
          int h = f >> 6, dh = f & 63;
          ((short*)Cp)[((size_t)((bb * 16 + h) * 64 + dh)) * 2048 + s] = f2bf(val);
        } else {
          int rowg = bm + wm * 64 + mt * 16 + lq * 4 + r;
          int colg = bn + wn * 64 + nt * 16 + l15;
          if (OMODE == OUT_HEAD) {
            int bb = rowg >> 11, s = rowg & 2047;
            int h = colg >> 6, dh = colg & 63;
            ((short*)Cp)[((size_t)(bb * 16 + h) * 2048 + s) * 64 + dh] = f2bf(val);
          } else {
            ((float*)Cp)[(size_t)rowg * 1024 + colg] = val;
          }
        }
      }
    }
  }
}

// XCD-aware tile mapping: 8 n-tiles of one A row-panel run consecutively on
// ONE XCD (id&7 = xcd under round-robin dispatch) -> A panel read once.
DI void xcd_map(int id, int& bm, int& bn) {
  int xcd = id & 7, slot = id >> 3;
  int panel = xcd + 8 * (slot >> 3);
  int ntile = slot & 7;
  bm = panel * 128;
  bn = ntile * 128;
}

#define GEMM_LDS()                                  \
  __shared__ __align__(16) short sA[2 * 128 * 64];  \
  __shared__ __align__(16) short sB[2 * 128 * 64];

__global__ __launch_bounds__(256) void proj_gemm3(
    const short* __restrict__ qb, const short* __restrict__ kb,
    const short* __restrict__ vb, const short* __restrict__ wq,
    const short* __restrict__ wk, const short* __restrict__ wv,
    short* __restrict__ xq, short* __restrict__ xk, short* __restrict__ xvT) {
  GEMM_LDS();
  int z = blockIdx.z;
  int bm, bn;
  xcd_map(blockIdx.x, bm, bn);
  if (z == 0) {
    gemm_core<OUT_HEAD>(sA, sB, qb, wq, xq, QSCALE, bm, bn);
  } else if (z == 1) {
    gemm_core<OUT_HEAD>(sA, sB, kb, wk, xk, 1.0f, bm, bn);
  } else {
    gemm_core<OUT_HEADT>(sA, sB, vb, wv, xvT, 1.0f, bm, bn);
  }
}

__global__ __launch_bounds__(256) void proj_oneN(
    const short* __restrict__ A, const short* __restrict__ B,
    short* __restrict__ C, float scale) {
  GEMM_LDS();
  int bm, bn;
  xcd_map(blockIdx.x, bm, bn);
  gemm_core<OUT_HEAD>(sA, sB, A, B, C, scale, bm, bn);
}

__global__ __launch_bounds__(256) void proj_oneT(
    const short* __restrict__ A, const short* __restrict__ B,
    short* __restrict__ C, float scale) {
  GEMM_LDS();
  int bm, bn;
  xcd_map(blockIdx.x, bm, bn);
  gemm_core<OUT_HEADT>(sA, sB, A, B, C, scale, bm, bn);
}

__global__ __launch_bounds__(256) void final_gemm(
    const short* __restrict__ oa, const short* __restrict__ wo,
    float* __restrict__ out) {
  GEMM_LDS();
  int bm, bn;
  xcd_map(blockIdx.x, bm, bn);
  gemm_core<OUT_F32>(sA, sB, oa, wo, out, 1.0f, bm, bn);
}

// ---------------------------------------------------------------------------
// Causal flash attention. R8/R9 structure, staging upgraded to
// global_load_lds (m151): linear LDS dest (wave wid -> rows wid*8..+7,
// HW lane*16) + inverse-swizzled global source (chunk = lch^lrr since
// (wid*8+lrr)&7 == lrr) + existing XOR'd ds_read -- same involution as the
// proven GEMM staging. gl16s for tile t+1 issue right after tile t's top
// barrier (buf[p^1] readers passed) and drain at t+1's __syncthreads.
// Removes 2x ds_write_b128 + 16 VGPR + per-lane addr math per thread/tile.
// LDS = 32KB (K,VT dbuf) + 16KB (P) = 48KB.
// ---------------------------------------------------------------------------
__global__ __launch_bounds__(512, 4) void attn_k(
    const short* __restrict__ Xq, const short* __restrict__ Xk,
    const short* __restrict__ XvT, short* __restrict__ Oa) {
  __shared__ __align__(16) short sK[2][64 * 64];
  __shared__ __align__(16) short sVT[2][64 * 64];
  __shared__ __align__(16) short sP[8][16 * 64];

  const int tid = threadIdx.x;
  const int lane = tid & 63;
  const int wid = tid >> 6;  // 0..7
  const int l15 = lane & 15, lq = lane >> 4;
  const int lrr = lane >> 3;  // 0..7: row within wave's 8-row group
  const int lch = lane & 7;   // 16B chunk within 128B row
  const int bid = blockIdx.x;
  const int ipair = bid >> 6;  // 0..7
  const int bh = bid & 63;     // same-bh blocks land on same XCD
  const int b = bh >> 4, h = bh & 15;

  const short* Q = Xq + (size_t)bh * 2048 * 64;
  const short* K = Xk + (size_t)bh * 2048 * 64;
  const short* VT = XvT + (size_t)bh * 64 * 2048;

  // gl16 staging geometry: wave wid covers rows wid*8 .. wid*8+7 of the
  // 64x64 tile; source chunk inverse-swizzled by lch^lrr.
  const int grow = wid * 8 + lrr;         // this lane's source row
  const int gsw = (lch ^ lrr) << 3;       // source chunk (shorts)
  short* const dK0 = (short*)sK[0] + wid * 8 * 64;
  short* const dK1 = (short*)sK[1] + wid * 8 * 64;
  short* const dV0 = (short*)sVT[0] + wid * 8 * 64;
  short* const dV1 = (short*)sVT[1] + wid * 8 * 64;

  // prologue: stage tile 0 (kv0 = 0) into buffer 0
  gl16(K + (size_t)grow * 64 + gsw, dK0);
  gl16(VT + (size_t)grow * 2048 + gsw, dV0);

  short* sPw = sP[wid];
  int p = 0;

  for (int seg = 0; seg < 2; ++seg) {
    const int qt = seg ? ipair : (15 - ipair);  // long supertile first
    const int qfirst = qt * 128 + wid * 16;
    const int qg = qfirst + l15;
    const int qlast = qfirst + 15;
    const int ntile = 2 * qt + 2;

    short8 qf[2];
#pragma unroll
    for (int ks = 0; ks < 2; ++ks)
      qf[ks] = *(const short8*)(Q + (size_t)qg * 64 + ks * 32 + lq * 8);

    float m_run = -1e30f, l_run = 0.f;
    f32x4 acc[4] = {};

    for (int kt = 0; kt < ntile; ++kt) {
      const int kv0 = kt * 64;
      __syncthreads();  // drains vmcnt(0): buf[p] (tile kt) landed, all waves

      // ---- issue next tile's gl16 into buf[p^1] (readers passed barrier) --
      int nkt = kt + 1, nseg = seg;
      if (nkt >= ntile) { nseg = seg + 1; nkt = 0; }
      const bool hn = (nseg < 2);
      if (hn) {
        const int kn = nkt * 64;
        gl16(K + (size_t)(kn + grow) * 64 + gsw, p ? dK0 : dK1);
        gl16(VT + (size_t)grow * 2048 + kn + gsw, p ? dV0 : dV1);
      }

      const bool fullmask = (kv0 > qlast);
      if (!fullmask) {
        const bool needmask = (kv0 + 63 > qfirst);
        const char* bufK = (const char*)sK[p];
        const char* bufV = (const char*)sVT[p];

        f32x4 sc[4] = {};
        __builtin_amdgcn_s_setprio(1);
#pragma unroll
        for (int ks = 0; ks < 2; ++ks) {
          short8 kf[4];
#pragma unroll
          for (int nt = 0; nt < 4; ++nt) {
            int row = nt * 16 + l15;
            int off = (row * 128 + ks * 64 + lq * 16) ^ ((row & 7) << 4);
            kf[nt] = *(const short8*)(bufK + off);
          }
#pragma unroll
          for (int nt = 0; nt < 4; ++nt)
            sc[nt] = __builtin_amdgcn_mfma_f32_16x16x32_bf16(kf[nt], qf[ks],
                                                             sc[nt], 0, 0, 0);
        }
        __builtin_amdgcn_s_setprio(0);

        float pv[4][4];
        float m = -1e30f;
        if (needmask) {
#pragma unroll
          for (int nt = 0; nt < 4; ++nt)
#pragma unroll
            for (int r = 0; r < 4; ++r) {
              float s = sc[nt][r];
              if (kv0 + nt * 16 + lq * 4 + r > qg) s = -1e30f;
              pv[nt][r] = s;
              m = fmaxf(m, s);
            }
        } else {
#pragma unroll
          for (int nt = 0; nt < 4; ++nt)
#pragma unroll
            for (int r = 0; r < 4; ++r) {
              float s = sc[nt][r];
              pv[nt][r] = s;
              m = fmaxf(m, s);
            }
        }
        m = fmaxf(m, __shfl_xor(m, 16));
        m = fmaxf(m, __shfl_xor(m, 32));

        if (!__all(m - m_run <= 8.0f)) {
          const float m_new = fmaxf(m_run, m);
          const float corr = fexp2(m_run - m_new);
          l_run *= corr;
#pragma unroll
          for (int mt = 0; mt < 4; ++mt)
#pragma unroll
            for (int r = 0; r < 4; ++r) acc[mt][r] *= corr;
          m_run = m_new;
        }

        float rsum = 0.f;
#pragma unroll
        for (int nt = 0; nt < 4; ++nt)
#pragma unroll
          for (int r = 0; r < 4; ++r) {
            float e = fexp2(pv[nt][r] - m_run);
            pv[nt][r] = e;
            rsum += e;
          }
        rsum += __shfl_xor(rsum, 16);
        rsum += __shfl_xor(rsum, 32);
        l_run += rsum;

#pragma unroll
        for (int nt = 0; nt < 4; ++nt) {
          short4v pw;
#pragma unroll
          for (int r = 0; r < 4; ++r) pw[r] = f2bf(pv[nt][r]);
          int off = (l15 * 128 + nt * 32 + lq * 8) ^ ((l15 & 7) << 4);
          *(short4v*)((char*)sPw + off) = pw;
        }

        __builtin_amdgcn_s_setprio(1);
#pragma unroll
        for (int ks = 0; ks < 2; ++ks) {
          int poff = (l15 * 128 + ks * 64 + lq * 16) ^ ((l15 & 7) << 4);
          short8 pf = *(const short8*)((const char*)sPw + poff);
#pragma unroll
          for (int mt = 0; mt < 4; ++mt) {
            int row = mt * 16 + l15;
            int voff = (row * 128 + ks * 64 + lq * 16) ^ ((row & 7) << 4);
            short8 vf = *(const short8*)(bufV + voff);
            acc[mt] = __builtin_amdgcn_mfma_f32_16x16x32_bf16(vf, pf, acc[mt],
                                                              0, 0, 0);
          }
        }
        __builtin_amdgcn_s_setprio(0);
      }

      p ^= 1;
    }

    const float rl = 1.0f / l_run;
    short* orow = Oa + ((size_t)(b * 2048 + qg)) * 1024 + h * 64;
#pragma unroll
    for (int mt = 0; mt < 4; ++mt) {
      short4v o;
#pragma unroll
      for (int r = 0; r < 4; ++r) o[r] = f2bf(acc[mt][r] * rl);
      *(short4v*)(orow + mt * 16 + lq * 4) = o;
    }
  }
}

// ---------------------------------------------------------------------------
extern "C" void kernel_launch(void* const* d_in, const int* in_sizes, int n_in,
                              void* d_out, int out_size, void* d_ws,
                              size_t ws_size, hipStream_t stream) {
  const float* q = (const float*)d_in[0];
  const float* k = (const float*)d_in[1];
  const float* v = (const float*)d_in[2];
  const float* Wq = (const float*)d_in[3];
  const float* Wk = (const float*)d_in[4];
  const float* Wv = (const float*)d_in[5];
  const float* Wo = (const float*)d_in[6];

  char* ws = (char*)d_ws;
  short* wq_b = (short*)(ws + (0ull << 20));
  short* wk_b = (short*)(ws + (2ull << 20));
  short* wv_b = (short*)(ws + (4ull << 20));
  short* wo_b = (short*)(ws + (6ull << 20));
  short* xq  = (short*)(ws + (8ull << 20));    // 16 MB each, [B,H,S,Dh] bf16
  short* xk  = (short*)(ws + (24ull << 20));
  short* xvT = (short*)(ws + (56ull << 20));   // [B,H,Dh,S] bf16

  if (ws_size >= (122ull << 20)) {
    short* qb = (short*)(ws + (72ull << 20));  // 16 MB each, [B*S, D] bf16
    short* kb = (short*)(ws + (88ull << 20));
    short* vb = (short*)(ws + (104ull << 20));
    short* oa = qb;  // qb dead after proj_gemm3

    convert_all<<<dim3(4096, 1, 7), 256, 0, stream>>>(q, k, v, Wq, Wk, Wv, Wo,
                                                      qb, kb, vb, wq_b);
    proj_gemm3<<<dim3(512, 1, 3), 256, 0, stream>>>(qb, kb, vb, wq_b, wk_b,
                                                    wv_b, xq, xk, xvT);
    attn_k<<<dim3(512), 512, 0, stream>>>(xq, xk, xvT, oa);
    final_gemm<<<dim3(512), 256, 0, stream>>>(oa, wo_b, (float*)d_out);
  } else {
    // ping-pong fallback: one 16 MB staging buffer, sequential per-z
    short* X = (short*)(ws + (8ull << 20));
    short* xq2 = (short*)(ws + (24ull << 20));
    short* xk2 = (short*)(ws + (40ull << 20));
    short* xvT2 = (short*)(ws + (56ull << 20));
    short* oa2 = (short*)(ws + (72ull << 20));

    convert_one<<<dim3(512), 256, 0, stream>>>(Wq, wq_b);
    convert_one<<<dim3(512), 256, 0, stream>>>(Wk, wk_b);
    convert_one<<<dim3(512), 256, 0, stream>>>(Wv, wv_b);
    convert_one<<<dim3(512), 256, 0, stream>>>(Wo, wo_b);
    convert_one<<<dim3(4096), 256, 0, stream>>>(q, X);
    proj_oneN<<<dim3(512), 256, 0, stream>>>(X, wq_b, xq2, QSCALE);
    convert_one<<<dim3(4096), 256, 0, stream>>>(k, X);
    proj_oneN<<<dim3(512), 256, 0, stream>>>(X, wk_b, xk2, 1.0f);
    convert_one<<<dim3(4096), 256, 0, stream>>>(v, X);
    proj_oneT<<<dim3(512), 256, 0, stream>>>(X, wv_b, xvT2, 1.0f);
    attn_k<<<dim3(512), 512, 0, stream>>>(xq2, xk2, xvT2, oa2);
    final_gemm<<<dim3(512), 256, 0, stream>>>(oa2, wo_b, (float*)d_out);
  }
}